// Round 6
// baseline (134.611 us; speedup 1.0000x reference)
//
#include <hip/hip_runtime.h>
#include <hip/hip_fp16.h>

#define S_LEN    1024
#define B_SZ     8
#define D_IN     64
#define D_OUT    96
#define NB       8
#define NE       (D_OUT * D_OUT)          // 9216
#define NT_C     512                      // 8 waves
#define HPAD     104                      // f16 row pitch (52 words: 8-row quads tile 32 banks; 52*48 ≡ 0 mod 32 so rows i and i+48 share the pattern)
#define SPAD     100                      // f32 row pitch

__device__ __forceinline__ float cos_rev(float v) {   // cos(2*pi*v), v in revolutions
    v -= floorf(v);
    return __builtin_amdgcn_cosf(v);
}

// In-block W generation (replaces w_kernel + HBM round-trip + stage_W).
// Same math as the session's proven hier_fallback: per (e,g) direct eval
// inv = rcp(e*8+2+g); cc = cos_rev(s*inv); W[e] = sum_g P[e][g]*cc, stored f16
// into the proven HPAD planar layout. Each thread owns e = tid + k*512
// (consecutive lanes -> consecutive e -> coalesced 32B/lane P loads and
// conflict-free ds_write_b16: 2 lanes/bank, free per m136).
__device__ __forceinline__ void gen_W(__half* __restrict__ wh,
                                      const float* __restrict__ P,
                                      float sf, int tid) {
    #pragma unroll 3
    for (int k = 0; k < NE / NT_C; ++k) {      // 18 elements per thread
        const int e = tid + k * NT_C;
        float pl[NB];
        *(float4*)&pl[0] = *(const float4*)(P + e * NB);
        *(float4*)&pl[4] = *(const float4*)(P + e * NB + 4);
        float acc = 0.0f;
        #pragma unroll
        for (int g = 0; g < NB; ++g) {
            const float inv = __builtin_amdgcn_rcpf((float)(e * NB + 2 + g));
            acc = fmaf(pl[g], cos_rev(sf * inv), acc);
        }
        const int i = (unsigned)e / D_OUT;     // e = i*96 + j
        const int j = (unsigned)e % D_OUT;
        wh[i * HPAD + j] = __float2half(acc);
    }
}

// Dual-row Nk dot: one x-row read (24 b128) feeds TWO W rows (i, i+48).
// fma order per output identical to the proven single-row nkdot. 8 lanes share
// each W row (broadcast); x rows conflict-free.  [r5-proven]
__device__ __forceinline__ void nkdot2(const __half* __restrict__ w0,
                                       const __half* __restrict__ w1,
                                       const float* __restrict__ xr,
                                       float& a0, float& a1) {
    #pragma unroll
    for (int h = 0; h < 2; ++h) {          // two 6-chunk halves bound in-flight regs
        #pragma unroll
        for (int j = h * 6; j < h * 6 + 6; ++j) {
            float4 xa = *(const float4*)(xr + 8 * j);
            float4 xb = *(const float4*)(xr + 8 * j + 4);
            float4 r0 = *(const float4*)(w0 + 8 * j);
            float4 r1 = *(const float4*)(w1 + 8 * j);
            const __half2* h0 = (const __half2*)&r0;
            const __half2* h1 = (const __half2*)&r1;
            float2 c;
            c = __half22float2(h0[0]); a0 = fmaf(c.x, xa.x, a0); a0 = fmaf(c.y, xa.y, a0);
            c = __half22float2(h0[1]); a0 = fmaf(c.x, xa.z, a0); a0 = fmaf(c.y, xa.w, a0);
            c = __half22float2(h0[2]); a0 = fmaf(c.x, xb.x, a0); a0 = fmaf(c.y, xb.y, a0);
            c = __half22float2(h0[3]); a0 = fmaf(c.x, xb.z, a0); a0 = fmaf(c.y, xb.w, a0);
            c = __half22float2(h1[0]); a1 = fmaf(c.x, xa.x, a1); a1 = fmaf(c.y, xa.y, a1);
            c = __half22float2(h1[1]); a1 = fmaf(c.x, xa.z, a1); a1 = fmaf(c.y, xa.w, a1);
            c = __half22float2(h1[2]); a1 = fmaf(c.x, xb.x, a1); a1 = fmaf(c.y, xb.y, a1);
            c = __half22float2(h1[3]); a1 = fmaf(c.x, xb.z, a1); a1 = fmaf(c.y, xb.w, a1);
        }
    }
}

// ---------------- Single kernel: r5 consumer skeleton + in-block W gen ------------
// 1024 blocks x 512 thr. No workspace, no producer dispatch, W never in HBM.
// (i,b) broadcast mapping everywhere (row-per-lane catastrophic r1; role-fused
// producer/consumer catastrophic r3 via shared regalloc; global-W nkdot regressed
// r4). gen_W math = hier_fallback-proven direct eval. LDS 29568 B.
__global__ void __launch_bounds__(NT_C)
consumer_direct(const float* __restrict__ seq,
                const float* __restrict__ M1, const float* __restrict__ Wres1,
                const float* __restrict__ M2,
                const float* __restrict__ g1, const float* __restrict__ b1,
                const float* __restrict__ g2, const float* __restrict__ b2,
                const float* __restrict__ P1, const float* __restrict__ P2,
                float* __restrict__ out) {
    __shared__ __align__(16) __half wh [D_OUT * HPAD];   // 19968 B (one layer at a time)
    __shared__ __align__(16) float  xn [B_SZ * SPAD];    //  3200 B
    __shared__ __align__(16) float  x1b[B_SZ * SPAD];    //  3200 B; xin alias pre-Nk1
    __shared__ __align__(16) float  rsb[B_SZ * SPAD];    //  3200 B residual

    const int s   = blockIdx.x;
    const int tid = threadIdx.x;
    const float sf = (float)s;

    // stage seq row + generate W1[s] into wh (disjoint LDS; both covered by B1)
    {
        int b = tid >> 6, k = tid & 63;
        x1b[b * SPAD + k] = seq[((size_t)b * S_LEN + s) * D_IN + k];   // xin alias
    }
    gen_W(wh, P1, sf, tid);
    __syncthreads();   // B1 (seq staged + W1 ready)

    // ---- GEMV1: xt = seq@M1^T -> xn;  rs = seq@Wres1^T -> rsb ----
    for (int pass = 0; pass < 2; ++pass) {
        int idx = tid + pass * NT_C;
        if (idx >= B_SZ * D_OUT) break;
        int i = idx >> 3, b = idx & 7;
        const float4* m  = (const float4*)(M1 + i * D_IN);
        const float4* wr = (const float4*)(Wres1 + i * D_IN);
        const float*  xr = x1b + b * SPAD;   // xin alias
        float at = 0.0f, ar = 0.0f;
        #pragma unroll
        for (int k = 0; k < D_IN / 4; ++k) {
            float4 mv = m[k], rv = wr[k];
            float x0 = xr[4*k], x1 = xr[4*k+1], x2 = xr[4*k+2], x3 = xr[4*k+3];
            at = fmaf(mv.x, x0, fmaf(mv.y, x1, fmaf(mv.z, x2, fmaf(mv.w, x3, at))));
            ar = fmaf(rv.x, x0, fmaf(rv.y, x1, fmaf(rv.z, x2, fmaf(rv.w, x3, ar))));
        }
        xn [b * SPAD + i] = at;
        rsb[b * SPAD + i] = ar;
    }
    __syncthreads();   // B2  (xin alias dead from here)

    // ---- LN1: wave64 per batch row ----
    {
        const int b = tid >> 6, lane = tid & 63;
        const bool lo = (lane < 32);
        float* row = xn + b * SPAD;
        float v0 = row[lane];
        float v1 = lo ? row[64 + lane] : 0.0f;
        float sum = v0 + v1, sq = fmaf(v0, v0, v1 * v1);
        #pragma unroll
        for (int off = 32; off > 0; off >>= 1) {
            sum += __shfl_down(sum, off, 64);
            sq  += __shfl_down(sq,  off, 64);
        }
        sum = __shfl(sum, 0, 64);
        sq  = __shfl(sq,  0, 64);
        const float mu  = sum * (1.0f / 96.0f);
        const float var = fmaf(sq, 1.0f / 96.0f, -(mu * mu));
        const float rs  = rsqrtf(var + 1e-5f);
        row[lane] = fmaf((v0 - mu) * rs, g1[lane], b1[lane]);
        if (lo) row[64 + lane] = fmaf((v1 - mu) * rs, g1[64 + lane], b1[64 + lane]);
    }
    __syncthreads();   // B3

    // ---- Nk1 + residual(rsb) -> x1b : dual-row, 384 threads ----
    if (tid < 8 * 48) {
        const int b  = tid & 7;
        const int ip = tid >> 3;              // rows ip, ip+48
        float a0 = 0.0f, a1 = 0.0f;
        nkdot2(wh + ip * HPAD, wh + (ip + 48) * HPAD, xn + b * SPAD, a0, a1);
        x1b[b * SPAD + ip]      = rsb[b * SPAD + ip]      + a0;
        x1b[b * SPAD + ip + 48] = rsb[b * SPAD + ip + 48] + a1;
    }
    __syncthreads();   // B4: W1 reads + x1b writes complete

    // regenerate wh <- W2[s] (overwrites; Nk1 done) + GEMV2 in the same region:
    // waves at different points mix trans-heavy gen_W with LDS/global GEMV2.
    gen_W(wh, P2, sf, tid);

    // ---- GEMV2: xt2 = x1 @ M2^T -> xn ----
    for (int pass = 0; pass < 2; ++pass) {
        int idx = tid + pass * NT_C;
        if (idx >= B_SZ * D_OUT) break;
        int i = idx >> 3, b = idx & 7;
        const float4* m  = (const float4*)(M2 + i * D_OUT);
        const float*  xr = x1b + b * SPAD;
        float at = 0.0f;
        #pragma unroll
        for (int k = 0; k < D_OUT / 4; ++k) {
            float4 mv = m[k];
            at = fmaf(mv.x, xr[4*k], fmaf(mv.y, xr[4*k+1],
                 fmaf(mv.z, xr[4*k+2], fmaf(mv.w, xr[4*k+3], at))));
        }
        xn[b * SPAD + i] = at;
    }
    __syncthreads();   // B5 (W2 ready + xn2 ready)

    // ---- LN2 ----
    {
        const int b = tid >> 6, lane = tid & 63;
        const bool lo = (lane < 32);
        float* row = xn + b * SPAD;
        float v0 = row[lane];
        float v1 = lo ? row[64 + lane] : 0.0f;
        float sum = v0 + v1, sq = fmaf(v0, v0, v1 * v1);
        #pragma unroll
        for (int off = 32; off > 0; off >>= 1) {
            sum += __shfl_down(sum, off, 64);
            sq  += __shfl_down(sq,  off, 64);
        }
        sum = __shfl(sum, 0, 64);
        sq  = __shfl(sq,  0, 64);
        const float mu  = sum * (1.0f / 96.0f);
        const float var = fmaf(sq, 1.0f / 96.0f, -(mu * mu));
        const float rs  = rsqrtf(var + 1e-5f);
        row[lane] = fmaf((v0 - mu) * rs, g2[lane], b2[lane]);
        if (lo) row[64 + lane] = fmaf((v1 - mu) * rs, g2[64 + lane], b2[64 + lane]);
    }
    __syncthreads();   // B6

    // ---- Nk2 + identity residual -> out : dual-row, 384 threads ----
    if (tid < 8 * 48) {
        const int b  = tid & 7;
        const int ip = tid >> 3;
        float a0 = 0.0f, a1 = 0.0f;
        nkdot2(wh + ip * HPAD, wh + (ip + 48) * HPAD, xn + b * SPAD, a0, a1);
        const size_t base = ((size_t)b * S_LEN + s) * D_OUT;
        out[base + ip]      = a0 + x1b[b * SPAD + ip];
        out[base + ip + 48] = a1 + x1b[b * SPAD + ip + 48];
    }
}

extern "C" void kernel_launch(void* const* d_in, const int* in_sizes, int n_in,
                              void* d_out, int out_size, void* d_ws, size_t ws_size,
                              hipStream_t stream) {
    const float* seq   = (const float*)d_in[0];
    const float* M1    = (const float*)d_in[1];
    const float* P1    = (const float*)d_in[2];
    const float* Wres1 = (const float*)d_in[3];
    const float* g1    = (const float*)d_in[4];
    const float* b1    = (const float*)d_in[5];
    const float* M2    = (const float*)d_in[6];
    const float* P2    = (const float*)d_in[7];
    const float* g2    = (const float*)d_in[8];
    const float* b2    = (const float*)d_in[9];
    float* out = (float*)d_out;
    (void)d_ws; (void)ws_size;   // workspace deliberately unused (fill-conditionality probe)

    consumer_direct<<<dim3(S_LEN), dim3(NT_C), 0, stream>>>(
        seq, M1, Wres1, M2, g1, b1, g2, b2, P1, P2, out);
}

// Round 7
// 119.238 us; speedup vs baseline: 1.1289x; 1.1289x over previous
//
#include <hip/hip_runtime.h>
#include <hip/hip_fp16.h>

#define S_LEN    1024
#define B_SZ     8
#define D_IN     64
#define D_OUT    96
#define NB       8
#define NE       (D_OUT * D_OUT)          // 9216
#define CHUNK    32                       // s-steps per recurrence chain
#define NCHUNK   (S_LEN / CHUNK)          // 32
#define NT_W     256
#define EPT      2                        // e per thread (half2 stores)
#define ESPAN    (NT_W * EPT)             // 512 e per producer block
#define NSLICE   (NE / ESPAN)             // 18 e-slices
#define NWBLK    (NCHUNK * NSLICE)        // 576 producer blocks
#define NT_C     512                      // 8 waves
#define HPAD     104                      // f16 row pitch (52 words: rows i..i+7 hit 8 distinct banks; 52*48 ≡ 0 mod 32 so i and i+48 share the pattern)
#define SPAD     100                      // f32 row pitch
#define XPAD     68

__device__ __forceinline__ float cos_rev(float v) {   // cos(2*pi*v), v in revolutions
    v -= floorf(v);
    return __builtin_amdgcn_cosf(v);
}

// ---------------- w_kernel: planar W1, W2 (f16) via cosine recurrence ----------------
// XCD-affinity: chunk c is produced entirely on XCD c%8 (bid ≡ c mod 8), so the
// consumer (same mapping) finds W[s] in its own XCD's L2 (1.2 MB/chunk << 4 MiB).
// EPT=2: each thread owns e0=2t, e0+1 -> half2 stores (256B/wave) + 2x ILP.
__global__ void __launch_bounds__(NT_W)
w_kernel(const float* __restrict__ P1, const float* __restrict__ P2,
         __half* __restrict__ W1, __half* __restrict__ W2) {
    const int x  = blockIdx.x & 7;            // XCD slot
    const int q  = blockIdx.x >> 3;           // 0..71
    const int c  = x + 8 * (q / NSLICE);      // chunk; c%8 == x
    const int eb = q % NSLICE;                // e-slice
    const int e0 = eb * ESPAN + EPT * threadIdx.x;
    const int s0 = c * CHUNK;
    const float s0f = (float)s0;

    float p1l[EPT][NB], p2l[EPT][NB], cc[EPT][NB], cp[EPT][NB], kk[EPT][NB];
    #pragma unroll
    for (int ee = 0; ee < EPT; ++ee) {
        *(float4*)&p1l[ee][0] = *(const float4*)(P1 + (e0 + ee) * NB);
        *(float4*)&p1l[ee][4] = *(const float4*)(P1 + (e0 + ee) * NB + 4);
        *(float4*)&p2l[ee][0] = *(const float4*)(P2 + (e0 + ee) * NB);
        *(float4*)&p2l[ee][4] = *(const float4*)(P2 + (e0 + ee) * NB + 4);
        #pragma unroll
        for (int g = 0; g < NB; ++g) {
            const float inv = __builtin_amdgcn_rcpf((float)((e0 + ee) * NB + 2 + g));
            cc[ee][g] = cos_rev(s0f * inv);
            cp[ee][g] = cos_rev((s0f - 1.0f) * inv);
            kk[ee][g] = 2.0f * __builtin_amdgcn_cosf(inv);   // inv <= 0.5 rev
        }
    }

    #pragma unroll 2
    for (int s = s0; s < s0 + CHUNK; ++s) {
        float a1[EPT], a2[EPT];
        #pragma unroll
        for (int ee = 0; ee < EPT; ++ee) {
            a1[ee] = 0.0f; a2[ee] = 0.0f;
            #pragma unroll
            for (int g = 0; g < NB; ++g) {
                a1[ee] = fmaf(p1l[ee][g], cc[ee][g], a1[ee]);
                a2[ee] = fmaf(p2l[ee][g], cc[ee][g], a2[ee]);
            }
        }
        *(__half2*)(W1 + s * NE + e0) = __floats2half2_rn(a1[0], a1[1]);   // 4B/lane
        *(__half2*)(W2 + s * NE + e0) = __floats2half2_rn(a2[0], a2[1]);
        #pragma unroll
        for (int ee = 0; ee < EPT; ++ee) {
            #pragma unroll
            for (int g = 0; g < NB; ++g) {
                float cn = fmaf(kk[ee][g], cc[ee][g], -cp[ee][g]);
                cp[ee][g] = cc[ee][g];
                cc[ee][g] = cn;
            }
        }
    }
}

// Dual-row Nk dot: one x-row read (24 b128) feeds TWO W rows (i, i+48).
// fma order per output identical to the proven single-row nkdot. 8 lanes share
// each W row (broadcast); x rows conflict-free.  [r5-proven]
__device__ __forceinline__ void nkdot2(const __half* __restrict__ w0,
                                       const __half* __restrict__ w1,
                                       const float* __restrict__ xr,
                                       float& a0, float& a1) {
    #pragma unroll
    for (int h = 0; h < 2; ++h) {          // two 6-chunk halves bound in-flight regs
        #pragma unroll
        for (int j = h * 6; j < h * 6 + 6; ++j) {
            float4 xa = *(const float4*)(xr + 8 * j);
            float4 xb = *(const float4*)(xr + 8 * j + 4);
            float4 r0 = *(const float4*)(w0 + 8 * j);
            float4 r1 = *(const float4*)(w1 + 8 * j);
            const __half2* h0 = (const __half2*)&r0;
            const __half2* h1 = (const __half2*)&r1;
            float2 c;
            c = __half22float2(h0[0]); a0 = fmaf(c.x, xa.x, a0); a0 = fmaf(c.y, xa.y, a0);
            c = __half22float2(h0[1]); a0 = fmaf(c.x, xa.z, a0); a0 = fmaf(c.y, xa.w, a0);
            c = __half22float2(h0[2]); a0 = fmaf(c.x, xb.x, a0); a0 = fmaf(c.y, xb.y, a0);
            c = __half22float2(h0[3]); a0 = fmaf(c.x, xb.z, a0); a0 = fmaf(c.y, xb.w, a0);
            c = __half22float2(h1[0]); a1 = fmaf(c.x, xa.x, a1); a1 = fmaf(c.y, xa.y, a1);
            c = __half22float2(h1[1]); a1 = fmaf(c.x, xa.z, a1); a1 = fmaf(c.y, xa.w, a1);
            c = __half22float2(h1[2]); a1 = fmaf(c.x, xb.x, a1); a1 = fmaf(c.y, xb.y, a1);
            c = __half22float2(h1[3]); a1 = fmaf(c.x, xb.z, a1); a1 = fmaf(c.y, xb.w, a1);
        }
    }
}

__device__ __forceinline__ void stage_W(__half* __restrict__ wh,
                                        const __half* __restrict__ Wg,
                                        int tid) {
    for (int cidx = tid; cidx < NE / 8; cidx += NT_C) {   // 1152 float4 chunks
        const int i = cidx / 12;
        const int j = (cidx % 12) * 8;
        *(float4*)(wh + i * HPAD + j) = *(const float4*)(Wg + cidx * 8);
    }
}

// ---------------- Consumer: r5 structure + XCD-affinity s mapping -----------------
// 512 thr = 8 waves; 1024 blocks = exactly 4/CU. Block bid handles s such that
// chunk(s)%8 == bid%8 -> W[s] was produced on this XCD (L2-resident).
// (i,b) broadcast mapping everywhere (row-per-lane catastrophic r1; role-fusion
// catastrophic r3; global-W nkdot regressed r4; per-block trig catastrophic r6).
__global__ void __launch_bounds__(NT_C)
consumer(const float* __restrict__ seq,
         const float* __restrict__ M1, const float* __restrict__ Wres1,
         const float* __restrict__ M2,
         const float* __restrict__ g1, const float* __restrict__ b1,
         const float* __restrict__ g2, const float* __restrict__ b2,
         const __half* __restrict__ W1g, const __half* __restrict__ W2g,
         float* __restrict__ out) {
    __shared__ __align__(16) __half wh [D_OUT * HPAD];   // 19968 B (one layer at a time)
    __shared__ __align__(16) float  xn [B_SZ * SPAD];    //  3200 B
    __shared__ __align__(16) float  x1b[B_SZ * SPAD];    //  3200 B; xin alias pre-Nk1
    __shared__ __align__(16) float  rsb[B_SZ * SPAD];    //  3200 B residual

    const int x = blockIdx.x & 7;
    const int y = blockIdx.x >> 3;                 // 0..127
    const int s = ((x + 8 * (y >> 5)) << 5) + (y & 31);   // chunk = x+8*(y>>5); bijective
    const int tid = threadIdx.x;

    // stage seq rows (into x1b alias space); W1 stage after B1 (drains at B2,
    // hidden under GEMV1 which never touches wh)  [r2-proven]
    {
        int b = tid >> 6, k = tid & 63;
        x1b[b * SPAD + k] = seq[((size_t)b * S_LEN + s) * D_IN + k];   // xin alias
    }
    __syncthreads();   // B1 (seq staged)

    stage_W(wh, W1g + (size_t)s * NE, tid);

    // ---- GEMV1: xt = seq@M1^T -> xn;  rs = seq@Wres1^T -> rsb ----
    for (int pass = 0; pass < 2; ++pass) {
        int idx = tid + pass * NT_C;
        if (idx >= B_SZ * D_OUT) break;
        int i = idx >> 3, b = idx & 7;
        const float4* m  = (const float4*)(M1 + i * D_IN);
        const float4* wr = (const float4*)(Wres1 + i * D_IN);
        const float*  xr = x1b + b * SPAD;   // xin alias
        float at = 0.0f, ar = 0.0f;
        #pragma unroll
        for (int k = 0; k < D_IN / 4; ++k) {
            float4 mv = m[k], rv = wr[k];
            float x0 = xr[4*k], x1 = xr[4*k+1], x2 = xr[4*k+2], x3 = xr[4*k+3];
            at = fmaf(mv.x, x0, fmaf(mv.y, x1, fmaf(mv.z, x2, fmaf(mv.w, x3, at))));
            ar = fmaf(rv.x, x0, fmaf(rv.y, x1, fmaf(rv.z, x2, fmaf(rv.w, x3, ar))));
        }
        xn [b * SPAD + i] = at;
        rsb[b * SPAD + i] = ar;
    }
    __syncthreads();   // B2  (xin alias dead from here; W1 staged)

    // ---- LN1: wave64 per batch row ----
    {
        const int b = tid >> 6, lane = tid & 63;
        const bool lo = (lane < 32);
        float* row = xn + b * SPAD;
        float v0 = row[lane];
        float v1 = lo ? row[64 + lane] : 0.0f;
        float sum = v0 + v1, sq = fmaf(v0, v0, v1 * v1);
        #pragma unroll
        for (int off = 32; off > 0; off >>= 1) {
            sum += __shfl_down(sum, off, 64);
            sq  += __shfl_down(sq,  off, 64);
        }
        sum = __shfl(sum, 0, 64);
        sq  = __shfl(sq,  0, 64);
        const float mu  = sum * (1.0f / 96.0f);
        const float var = fmaf(sq, 1.0f / 96.0f, -(mu * mu));
        const float rs  = rsqrtf(var + 1e-5f);
        row[lane] = fmaf((v0 - mu) * rs, g1[lane], b1[lane]);
        if (lo) row[64 + lane] = fmaf((v1 - mu) * rs, g1[64 + lane], b1[64 + lane]);
    }
    __syncthreads();   // B3

    // ---- Nk1 + residual(rsb) -> x1b : dual-row, 384 threads ----
    if (tid < 8 * 48) {
        const int b  = tid & 7;
        const int ip = tid >> 3;              // rows ip, ip+48
        float a0 = 0.0f, a1 = 0.0f;
        nkdot2(wh + ip * HPAD, wh + (ip + 48) * HPAD, xn + b * SPAD, a0, a1);
        x1b[b * SPAD + ip]      = rsb[b * SPAD + ip]      + a0;
        x1b[b * SPAD + ip + 48] = rsb[b * SPAD + ip + 48] + a1;
    }
    __syncthreads();   // B4: W1 reads + x1b writes complete

    // restage wh <- W2[s]; GEMV2 overlaps (doesn't touch wh), B5 covers both.
    stage_W(wh, W2g + (size_t)s * NE, tid);

    // ---- GEMV2: xt2 = x1 @ M2^T -> xn ----
    for (int pass = 0; pass < 2; ++pass) {
        int idx = tid + pass * NT_C;
        if (idx >= B_SZ * D_OUT) break;
        int i = idx >> 3, b = idx & 7;
        const float4* m  = (const float4*)(M2 + i * D_OUT);
        const float*  xr = x1b + b * SPAD;
        float at = 0.0f;
        #pragma unroll
        for (int k = 0; k < D_OUT / 4; ++k) {
            float4 mv = m[k];
            at = fmaf(mv.x, xr[4*k], fmaf(mv.y, xr[4*k+1],
                 fmaf(mv.z, xr[4*k+2], fmaf(mv.w, xr[4*k+3], at))));
        }
        xn[b * SPAD + i] = at;
    }
    __syncthreads();   // B5

    // ---- LN2 ----
    {
        const int b = tid >> 6, lane = tid & 63;
        const bool lo = (lane < 32);
        float* row = xn + b * SPAD;
        float v0 = row[lane];
        float v1 = lo ? row[64 + lane] : 0.0f;
        float sum = v0 + v1, sq = fmaf(v0, v0, v1 * v1);
        #pragma unroll
        for (int off = 32; off > 0; off >>= 1) {
            sum += __shfl_down(sum, off, 64);
            sq  += __shfl_down(sq,  off, 64);
        }
        sum = __shfl(sum, 0, 64);
        sq  = __shfl(sq,  0, 64);
        const float mu  = sum * (1.0f / 96.0f);
        const float var = fmaf(sq, 1.0f / 96.0f, -(mu * mu));
        const float rs  = rsqrtf(var + 1e-5f);
        row[lane] = fmaf((v0 - mu) * rs, g2[lane], b2[lane]);
        if (lo) row[64 + lane] = fmaf((v1 - mu) * rs, g2[64 + lane], b2[64 + lane]);
    }
    __syncthreads();   // B6

    // ---- Nk2 + identity residual -> out : dual-row, 384 threads ----
    if (tid < 8 * 48) {
        const int b  = tid & 7;
        const int ip = tid >> 3;
        float a0 = 0.0f, a1 = 0.0f;
        nkdot2(wh + ip * HPAD, wh + (ip + 48) * HPAD, xn + b * SPAD, a0, a1);
        const size_t base = ((size_t)b * S_LEN + s) * D_OUT;
        out[base + ip]      = a0 + x1b[b * SPAD + ip];
        out[base + ip + 48] = a1 + x1b[b * SPAD + ip + 48];
    }
}

// ---------------- Fallback (round-1 proven kernel) if ws too small ----------------
__global__ void __launch_bounds__(NT_W)
hier_fallback(const float* __restrict__ seq,  const float* __restrict__ M1,
              const float* __restrict__ P1,   const float* __restrict__ Wres1,
              const float* __restrict__ g1,   const float* __restrict__ b1,
              const float* __restrict__ M2,   const float* __restrict__ P2,
              const float* __restrict__ g2,   const float* __restrict__ b2,
              float* __restrict__ out) {
    __shared__ __align__(16) float w[D_OUT * SPAD];
    __shared__ __align__(16) float xin[B_SZ * XPAD];
    __shared__ __align__(16) float xn [B_SZ * SPAD];
    __shared__ __align__(16) float x1b[B_SZ * SPAD];
    const int s = blockIdx.x, tid = threadIdx.x;
    const float sf = (float)s;

    for (int idx = tid; idx < B_SZ * D_IN; idx += NT_W) {
        int b = idx >> 6, k = idx & (D_IN - 1);
        xin[b * XPAD + k] = seq[(b * S_LEN + s) * D_IN + k];
    }
    for (int e = tid; e < NE; e += NT_W) {
        float pl[8];
        *(float4*)&pl[0] = *(const float4*)(P1 + e * NB);
        *(float4*)&pl[4] = *(const float4*)(P1 + e * NB + 4);
        float acc = 0.0f;
        #pragma unroll
        for (int g = 0; g < NB; ++g) {
            float v = sf * __builtin_amdgcn_rcpf((float)(e * NB + 2 + g));
            acc = fmaf(pl[g], cos_rev(v), acc);
        }
        int i = e / D_OUT;
        w[e + (SPAD - D_OUT) * i] = acc;
    }
    __syncthreads();
    for (int idx = tid; idx < B_SZ * D_OUT; idx += NT_W) {
        int i = idx >> 3, b = idx & 7;
        const float4* m  = (const float4*)(M1 + i * D_IN);
        const float4* wr = (const float4*)(Wres1 + i * D_IN);
        const float*  xr = xin + b * XPAD;
        float at = 0.0f, ar = 0.0f;
        #pragma unroll
        for (int k = 0; k < D_IN / 4; ++k) {
            float4 mv = m[k], rv = wr[k];
            float x0 = xr[4*k], x1 = xr[4*k+1], x2 = xr[4*k+2], x3 = xr[4*k+3];
            at = fmaf(mv.x, x0, fmaf(mv.y, x1, fmaf(mv.z, x2, fmaf(mv.w, x3, at))));
            ar = fmaf(rv.x, x0, fmaf(rv.y, x1, fmaf(rv.z, x2, fmaf(rv.w, x3, ar))));
        }
        xn [b * SPAD + i] = at;
        x1b[b * SPAD + i] = ar;
    }
    __syncthreads();
    {
        const int b = tid >> 5, rr = tid & 31;
        float* row = xn + b * SPAD;
        float v0 = row[rr], v1 = row[rr + 32], v2 = row[rr + 64];
        float sum = v0 + v1 + v2, sq = fmaf(v0, v0, fmaf(v1, v1, v2 * v2));
        #pragma unroll
        for (int off = 16; off > 0; off >>= 1) {
            sum += __shfl_down(sum, off, 32);
            sq  += __shfl_down(sq,  off, 32);
        }
        sum = __shfl(sum, 0, 32); sq = __shfl(sq, 0, 32);
        float mu = sum * (1.0f/96.0f), var = fmaf(sq, 1.0f/96.0f, -(mu*mu));
        float rs = rsqrtf(var + 1e-5f);
        row[rr]      = fmaf((v0 - mu) * rs, g1[rr],      b1[rr]);
        row[rr + 32] = fmaf((v1 - mu) * rs, g1[rr + 32], b1[rr + 32]);
        row[rr + 64] = fmaf((v2 - mu) * rs, g1[rr + 64], b1[rr + 64]);
    }
    __syncthreads();
    for (int idx = tid; idx < B_SZ * D_OUT; idx += NT_W) {
        int i = idx >> 3, b = idx & 7;
        const float* wrow = w + i * SPAD;
        const float* xr   = xn + b * SPAD;
        float acc = 0.0f;
        #pragma unroll
        for (int j = 0; j < D_OUT / 4; ++j) {
            float4 wv = *(const float4*)(wrow + 4 * j);
            float4 xv = *(const float4*)(xr + 4 * j);
            acc = fmaf(wv.x, xv.x, fmaf(wv.y, xv.y, fmaf(wv.z, xv.z, fmaf(wv.w, xv.w, acc))));
        }
        x1b[b * SPAD + i] += acc;
    }
    __syncthreads();
    for (int e = tid; e < NE; e += NT_W) {
        float pl[8];
        *(float4*)&pl[0] = *(const float4*)(P2 + e * NB);
        *(float4*)&pl[4] = *(const float4*)(P2 + e * NB + 4);
        float acc = 0.0f;
        #pragma unroll
        for (int g = 0; g < NB; ++g) {
            float v = sf * __builtin_amdgcn_rcpf((float)(e * NB + 2 + g));
            acc = fmaf(pl[g], cos_rev(v), acc);
        }
        int i = e / D_OUT;
        w[e + (SPAD - D_OUT) * i] = acc;
    }
    for (int idx = tid; idx < B_SZ * D_OUT; idx += NT_W) {
        int i = idx >> 3, b = idx & 7;
        const float4* m  = (const float4*)(M2 + i * D_OUT);
        const float*  xr = x1b + b * SPAD;
        float at = 0.0f;
        #pragma unroll
        for (int k = 0; k < D_OUT / 4; ++k) {
            float4 mv = m[k];
            at = fmaf(mv.x, xr[4*k], fmaf(mv.y, xr[4*k+1],
                 fmaf(mv.z, xr[4*k+2], fmaf(mv.w, xr[4*k+3], at))));
        }
        xn[b * SPAD + i] = at;
    }
    __syncthreads();
    {
        const int b = tid >> 5, rr = tid & 31;
        float* row = xn + b * SPAD;
        float v0 = row[rr], v1 = row[rr + 32], v2 = row[rr + 64];
        float sum = v0 + v1 + v2, sq = fmaf(v0, v0, fmaf(v1, v1, v2 * v2));
        #pragma unroll
        for (int off = 16; off > 0; off >>= 1) {
            sum += __shfl_down(sum, off, 32);
            sq  += __shfl_down(sq,  off, 32);
        }
        sum = __shfl(sum, 0, 32); sq = __shfl(sq, 0, 32);
        float mu = sum * (1.0f/96.0f), var = fmaf(sq, 1.0f/96.0f, -(mu*mu));
        float rs = rsqrtf(var + 1e-5f);
        row[rr]      = fmaf((v0 - mu) * rs, g2[rr],      b2[rr]);
        row[rr + 32] = fmaf((v1 - mu) * rs, g2[rr + 32], b2[rr + 32]);
        row[rr + 64] = fmaf((v2 - mu) * rs, g2[rr + 64], b2[rr + 64]);
    }
    __syncthreads();
    for (int idx = tid; idx < B_SZ * D_OUT; idx += NT_W) {
        int i = idx >> 3, b = idx & 7;
        const float* wrow = w + i * SPAD;
        const float* xr   = xn + b * SPAD;
        float acc = 0.0f;
        #pragma unroll
        for (int j = 0; j < D_OUT / 4; ++j) {
            float4 wv = *(const float4*)(wrow + 4 * j);
            float4 xv = *(const float4*)(xr + 4 * j);
            acc = fmaf(wv.x, xv.x, fmaf(wv.y, xv.y, fmaf(wv.z, xv.z, fmaf(wv.w, xv.w, acc))));
        }
        out[(b * S_LEN + s) * D_OUT + i] = acc + x1b[b * SPAD + i];
    }
}

extern "C" void kernel_launch(void* const* d_in, const int* in_sizes, int n_in,
                              void* d_out, int out_size, void* d_ws, size_t ws_size,
                              hipStream_t stream) {
    const float* seq   = (const float*)d_in[0];
    const float* M1    = (const float*)d_in[1];
    const float* P1    = (const float*)d_in[2];
    const float* Wres1 = (const float*)d_in[3];
    const float* g1    = (const float*)d_in[4];
    const float* b1    = (const float*)d_in[5];
    const float* M2    = (const float*)d_in[6];
    const float* P2    = (const float*)d_in[7];
    const float* g2    = (const float*)d_in[8];
    const float* b2    = (const float*)d_in[9];
    float* out = (float*)d_out;

    const size_t need = (size_t)2 * S_LEN * NE * sizeof(__half);   // 37.75 MB
    if (ws_size >= need) {
        __half* W1 = (__half*)d_ws;
        __half* W2 = W1 + (size_t)S_LEN * NE;
        w_kernel<<<dim3(NWBLK), dim3(NT_W), 0, stream>>>(P1, P2, W1, W2);
        consumer<<<dim3(S_LEN), dim3(NT_C), 0, stream>>>(
            seq, M1, Wres1, M2, g1, b1, g2, b2, W1, W2, out);
    } else {
        hier_fallback<<<dim3(S_LEN), dim3(NT_W), 0, stream>>>(
            seq, M1, P1, Wres1, g1, b1, M2, P2, g2, b2, out);
    }
}